// Round 3
// baseline (216.773 us; speedup 1.0000x reference)
//
#include <hip/hip_runtime.h>
#include <math.h>

#define HFD 128
#define WFD 128
#define DFD 512
#define KA  4
#define NA  (HFD*WFD*KA)      // 65536
#define MAXD 512
#define HID 1024
#define FIN 4608              // 3*3*512
#define CMAX 2048
#define NBUCK 1025
#define BINCAP 64
#define TAUF 0.5f
#define NMS_THR 0.3f
#define SPLITK 4

typedef __bf16 bf16x8 __attribute__((ext_vector_type(8)));
typedef float  floatx4 __attribute__((ext_vector_type(4)));

__device__ __forceinline__ unsigned short f2bf(float x) {
    unsigned u = __float_as_uint(x);
    unsigned r = (u + 0x7FFFu + ((u >> 16) & 1u)) >> 16;   // RNE
    return (unsigned short)r;
}

// ---- grid-wide front: score+bucket-bin (blocks 0..255) + transposes
__global__ __launch_bounds__(256)
void front_kernel(const float* __restrict__ rpn_obj,
                  unsigned* __restrict__ hist,
                  unsigned long long* __restrict__ bins,
                  const float* __restrict__ W1,
                  unsigned short* __restrict__ W1t,
                  const float* __restrict__ W2,
                  unsigned short* __restrict__ W2t) {
    __shared__ float tile[32][33];
    int b = blockIdx.x;
    if (b < 256) {
        int n = b * 256 + threadIdx.x;
        float2 o = ((const float2*)rpn_obj)[n];
        float m  = fmaxf(o.x, o.y);
        float e0 = expf(o.x - m), e1 = expf(o.y - m);
        float s  = e1 / (e0 + e1);
        if (s > TAUF) {
            unsigned bits = __float_as_uint(s);
            unsigned bk = (bits - 0x3F000000u) >> 13;     // 0..1024
            unsigned slot = atomicAdd(&hist[bk], 1u);
            if (slot < BINCAP)
                bins[bk * BINCAP + slot] =
                    ((unsigned long long)bits << 32) |
                    (unsigned long long)(~(unsigned)n);
        }
        return;
    }
    b -= 256;
    const float* W; unsigned short* Wt; int K, N;
    if (b < (FIN / 32) * (HID / 32)) { W = W1; Wt = W1t; K = FIN; N = HID; }
    else { b -= (FIN / 32) * (HID / 32); W = W2; Wt = W2t; K = HID; N = HID; }
    int bn = (b & (N / 32 - 1)) * 32;
    int bk = (b / (N / 32)) * 32;
    int tx = threadIdx.x & 31, ty = threadIdx.x >> 5;     // ty 0..7
#pragma unroll
    for (int r = 0; r < 32; r += 8)
        tile[ty + r][tx] = W[(long)(bk + ty + r) * N + bn + tx];
    __syncthreads();
#pragma unroll
    for (int r = 0; r < 32; r += 8)
        Wt[(long)(bn + ty + r) * K + bk + tx] = f2bf(tile[tx][ty + r]);
}

// ---- single block: threshold + parallel gather + sort + decode
__global__ __launch_bounds__(1024)
void tgs_kernel(const unsigned* __restrict__ hist,
                const unsigned long long* __restrict__ bins,
                const float* __restrict__ rpn_reg,
                const float* __restrict__ anchors,
                float* __restrict__ sel,          // 512 x float4
                float* __restrict__ top_score,    // 512
                unsigned* __restrict__ valid_g) { // 512
    __shared__ unsigned long long keys[CMAX];     // 16 KB
    __shared__ unsigned Hs[NBUCK];                // 4.1 KB
    __shared__ unsigned Ssc[1024];                // 4 KB
    __shared__ unsigned cntS;
    __shared__ unsigned thrS;

    int tid = threadIdx.x;
    int wave = tid >> 6, lane = tid & 63;

    // ---- phase A: load hist, suffix-sum buckets 1..1024, find threshold
    if (tid == 0) cntS = 0u;
    for (int i = tid; i < NBUCK; i += 1024) Hs[i] = hist[i];
    __syncthreads();
    unsigned sv = Hs[tid + 1];                    // thread t <-> bucket t+1
    Ssc[tid] = sv;
    __syncthreads();
    for (int d = 1; d < 1024; d <<= 1) {
        unsigned add = (tid + d < 1024) ? Ssc[tid + d] : 0u;
        __syncthreads();
        Ssc[tid] += add;
        __syncthreads();
    }
    if (tid == 0 && Ssc[0] < MAXD) thrS = 0u;
    {
        unsigned Scur = Ssc[tid];
        unsigned Snxt = (tid == 1023) ? 0u : Ssc[tid + 1];
        if (Scur >= MAXD && Snxt < MAXD) thrS = (unsigned)(tid + 1);
    }
    __syncthreads();
    unsigned thr = thrS;

    // ---- phase B: wave-per-bucket PARALLEL gather (lane i -> slot i)
    for (int b = (int)thr + wave; b < NBUCK; b += 16) {
        unsigned c = Hs[b]; if (c > BINCAP) c = BINCAP;
        unsigned base = 0;
        if (lane == 0 && c > 0) base = atomicAdd(&cntS, c);
        base = __shfl(base, 0);
        if (c > 0 && lane < c && base + lane < CMAX)
            keys[base + lane] = bins[(long)b * BINCAP + lane];
    }
    __syncthreads();
    unsigned cnt = cntS; if (cnt > CMAX) cnt = CMAX;
    int SN = (cnt <= 1024) ? 1024 : CMAX;
    for (int i = tid; i < SN; i += 1024)
        if (i >= (int)cnt) keys[i] = 0ULL;
    __syncthreads();

    // ---- phase C: bitonic sort descending over SN
    for (int k = 2; k <= SN; k <<= 1) {
        for (int j = k >> 1; j > 0; j >>= 1) {
            for (int i = tid; i < SN; i += 1024) {
                int ixj = i ^ j;
                if (ixj > i) {
                    unsigned long long a = keys[i], b = keys[ixj];
                    bool up = ((i & k) == 0);
                    if ((a < b) == up) { keys[i] = b; keys[ixj] = a; }
                }
            }
            __syncthreads();
        }
    }

    // ---- phase D: decode top-512 boxes (same fp32 formulas)
    if (tid < MAXD) {
        unsigned long long e = keys[tid];
        unsigned sbits = (unsigned)(e >> 32);
        bool v = (sbits != 0u);
        unsigned idx = v ? (unsigned)(~(unsigned)e) : 0u;
        int cell = idx >> 2, kk = idx & 3;
        float4 rg = *(const float4*)&rpn_reg[cell * 16 + 4 * kk];
        float4 an = *(const float4*)&anchors[idx * 4];
        float acx = an.x + an.z * 0.5f;
        float acy = an.y + an.w * 0.5f;
        float cx = acx + rg.x * an.z;
        float cy = acy + rg.y * an.w;
        float w  = an.z * expf(rg.z);
        float h  = an.w * expf(rg.w);
        ((float4*)sel)[tid] = make_float4(cx - 0.5f * w, cy - 0.5f * h, w, h);
        top_score[tid] = v ? __uint_as_float(sbits) : 0.0f;
        valid_g[tid]   = v ? 1u : 0u;
    }
}

// ---------------------------------------------------- IoU bitmask
__global__ __launch_bounds__(512)
void iou_mask_kernel(const float* __restrict__ sel,
                     unsigned long long* __restrict__ mask) {
    int i = blockIdx.x;
    int j = threadIdx.x;
    float4 bi = ((const float4*)sel)[i];
    float4 bj = ((const float4*)sel)[j];
    float x2i = bi.x + bi.z, y2i = bi.y + bi.w;
    float x2j = bj.x + bj.z, y2j = bj.y + bj.w;
    float ai = bi.z * bi.w, aj = bj.z * bj.w;
    float ix = fmaxf(0.0f, fminf(x2i, x2j) - fmaxf(bi.x, bj.x));
    float iy = fmaxf(0.0f, fminf(y2i, y2j) - fmaxf(bi.y, bj.y));
    float inter = ix * iy;
    float iou = inter / (ai + aj - inter + 1e-8f);
    unsigned long long bal = __ballot(iou > NMS_THR);
    if ((j & 63) == 0) mask[i * 8 + (j >> 6)] = bal;
}

// ------------------- sequential NMS, column-owner wave scan (1 wave)
// Lane l owns columns {g*64+l}. supp8 bit g = column g*64+l suppressed.
// IoU matrix is symmetric, so within score-group G only word G of each
// owned row is needed -> 8 loads/group, all indices compile-time static
// (NO scratch: the old version spilled w[8][8] and stalled 89 us).
__global__ __launch_bounds__(64, 1)
void nms_scan_kernel(const unsigned long long* __restrict__ mask,
                     const unsigned* __restrict__ valid,
                     unsigned* __restrict__ keep) {
    int lane = threadIdx.x;
    unsigned long long vb[8];
#pragma unroll
    for (int g = 0; g < 8; ++g)
        vb[g] = __ballot(valid[g * 64 + lane] != 0u);

    unsigned long long cw[8], cwn[8];
#pragma unroll
    for (int g = 0; g < 8; ++g)
        cw[g] = mask[(g * 64 + lane) * 8 + 0];

    unsigned supp8 = 0u;
#pragma unroll
    for (int G = 0; G < 8; ++G) {
        if (G < 7) {
#pragma unroll
            for (int g = 0; g < 8; ++g)
                cwn[g] = mask[(g * 64 + lane) * 8 + (G + 1)];
        }
        unsigned long long kg = 0ULL;
        unsigned long long vbG = vb[G];
        for (int b = 0; b < 64; ++b) {
            unsigned long long sg = __ballot((supp8 >> G) & 1u);
            unsigned long long bi = 1ULL << b;
            if (((vbG & bi) != 0ULL) && ((sg & bi) == 0ULL)) {  // uniform
                kg |= bi;
                unsigned nb = 0u;
#pragma unroll
                for (int g = 0; g < 8; ++g)
                    nb |= (unsigned)((cw[g] >> b) & 1ULL) << g;
                supp8 |= nb;
            }
        }
        keep[G * 64 + lane] = (unsigned)((kg >> lane) & 1ULL);
#pragma unroll
        for (int g = 0; g < 8; ++g) cw[g] = cwn[g];
    }
}

// ---- ROI align, tile-split: 9 blocks per ROI (one per output tile)
__global__ __launch_bounds__(256)
void roialign_kernel(const float* __restrict__ feat,
                     const float* __restrict__ sel,
                     unsigned short* __restrict__ pooled) {
    int blk = blockIdx.x;             // 0 .. MAXD*9-1
    int mrow = blk / 9;
    int tile = blk - mrow * 9;        // (p>>1)*3 + (q>>1)
    int tp = tile / 3, tq = tile - tp * 3;
    int c = threadIdx.x;              // channels c and c+256
    float4 b = ((const float4*)sel)[mrow];
    float vmax0 = -INFINITY, vmax1 = -INFINITY;
#pragma unroll
    for (int dp = 0; dp < 2; ++dp) {
        int p = tp * 2 + dp;
        float fy = (b.y + ((float)p + 0.5f) / 6.0f * b.w) / 16.0f - 0.5f;
        fy = fminf(fmaxf(fy, 0.0f), 127.0f);
        int y0 = (int)floorf(fy);
        int y1 = min(y0 + 1, 127);
        float wy = fy - (float)y0;
#pragma unroll
        for (int dq = 0; dq < 2; ++dq) {
            int q = tq * 2 + dq;
            float fx = (b.x + ((float)q + 0.5f) / 6.0f * b.z) / 16.0f - 0.5f;
            fx = fminf(fmaxf(fx, 0.0f), 127.0f);
            int x0 = (int)floorf(fx);
            int x1 = min(x0 + 1, 127);
            float wx = fx - (float)x0;
            const float* f00 = feat + (y0 * WFD + x0) * DFD;
            const float* f01 = feat + (y0 * WFD + x1) * DFD;
            const float* f10 = feat + (y1 * WFD + x0) * DFD;
            const float* f11 = feat + (y1 * WFD + x1) * DFD;
            float w00 = (1.0f - wy) * (1.0f - wx);
            float w01 = (1.0f - wy) * wx;
            float w10 = wy * (1.0f - wx);
            float w11 = wy * wx;
            float v0 = f00[c] * w00 + f01[c] * w01 + f10[c] * w10 + f11[c] * w11;
            float v1 = f00[c + 256] * w00 + f01[c + 256] * w01 +
                       f10[c + 256] * w10 + f11[c + 256] * w11;
            vmax0 = fmaxf(vmax0, v0);
            vmax1 = fmaxf(vmax1, v1);
        }
    }
    pooled[mrow * FIN + tile * DFD + c] = f2bf(vmax0);
    pooled[mrow * FIN + tile * DFD + c + 256] = f2bf(vmax1);
}

// --------------------------------------- bf16 MFMA GEMM with split-K
// BK=64: 8 MFMAs per wave between barrier pairs
#define LDK 72
__global__ __launch_bounds__(256)
void mfma_gemm_kernel(const unsigned short* __restrict__ A,
                      const unsigned short* __restrict__ Bt,
                      float* __restrict__ Cpart,
                      int M, int N, int K) {
    __shared__ unsigned short As[64 * LDK];
    __shared__ unsigned short Bs[64 * LDK];
    int tid = threadIdx.x;
    int wave = tid >> 6, lane = tid & 63;
    int bm = blockIdx.y * 64, bn = blockIdx.x * 64;
    int KC = K / SPLITK;
    int ks = blockIdx.z * KC;

    floatx4 acc[4] = {};
    int lr = tid >> 2;            // 0..63  staging row
    int lk = (tid & 3) << 4;      // 0,16,32,48  staging k-offset (shorts)
    int frow = lane & 15, quad = lane >> 4;

    const unsigned short* Ap = A + (long)(bm + lr) * K + lk;
    const unsigned short* Bp = Bt + (long)(bn + lr) * K + lk;

    for (int k0 = ks; k0 < ks + KC; k0 += 64) {
        uint4 a0 = *(const uint4*)(Ap + k0);
        uint4 a1 = *(const uint4*)(Ap + k0 + 8);
        uint4 b0 = *(const uint4*)(Bp + k0);
        uint4 b1 = *(const uint4*)(Bp + k0 + 8);
        *(uint4*)&As[lr * LDK + lk] = a0;
        *(uint4*)&As[lr * LDK + lk + 8] = a1;
        *(uint4*)&Bs[lr * LDK + lk] = b0;
        *(uint4*)&Bs[lr * LDK + lk + 8] = b1;
        __syncthreads();
        bf16x8 af0 = *(const bf16x8*)&As[(wave * 16 + frow) * LDK + quad * 8];
        bf16x8 af1 = *(const bf16x8*)&As[(wave * 16 + frow) * LDK + 32 + quad * 8];
#pragma unroll
        for (int t = 0; t < 4; ++t) {
            bf16x8 b0v = *(const bf16x8*)&Bs[(t * 16 + frow) * LDK + quad * 8];
            bf16x8 b1v = *(const bf16x8*)&Bs[(t * 16 + frow) * LDK + 32 + quad * 8];
            acc[t] = __builtin_amdgcn_mfma_f32_16x16x32_bf16(af0, b0v, acc[t], 0, 0, 0);
            acc[t] = __builtin_amdgcn_mfma_f32_16x16x32_bf16(af1, b1v, acc[t], 0, 0, 0);
        }
        __syncthreads();
    }

    float* Cp = Cpart + (long)blockIdx.z * M * N;
#pragma unroll
    for (int t = 0; t < 4; ++t) {
#pragma unroll
        for (int r = 0; r < 4; ++r) {
            int m = bm + wave * 16 + quad * 4 + r;
            int n = bn + t * 16 + frow;
            Cp[(long)m * N + n] = acc[t][r];
        }
    }
}

// --------------------- split-K reduce + bias + relu -> bf16
__global__ __launch_bounds__(256)
void reduce_bias_relu_kernel(const float* __restrict__ Cpart,
                             const float* __restrict__ bias,
                             unsigned short* __restrict__ out_bf,
                             int MN, int N) {
    int i4 = (blockIdx.x * blockDim.x + threadIdx.x) * 4;
    if (i4 >= MN) return;
    float4 s = *(const float4*)&Cpart[i4];
#pragma unroll
    for (int z = 1; z < SPLITK; ++z) {
        float4 p = *(const float4*)&Cpart[(long)z * MN + i4];
        s.x += p.x; s.y += p.y; s.z += p.z; s.w += p.w;
    }
    int n = i4 & (N - 1);
    float4 bi = *(const float4*)&bias[n];
    s.x = fmaxf(s.x + bi.x, 0.0f);
    s.y = fmaxf(s.y + bi.y, 0.0f);
    s.z = fmaxf(s.z + bi.z, 0.0f);
    s.w = fmaxf(s.w + bi.w, 0.0f);
    uint2 o;
    o.x = (unsigned)f2bf(s.x) | ((unsigned)f2bf(s.y) << 16);
    o.y = (unsigned)f2bf(s.z) | ((unsigned)f2bf(s.w) << 16);
    *(uint2*)&out_bf[i4] = o;
}

// --- fused: split-K reduce (GEMM2) + bias2 + relu + W3 dot + epilogue
__global__ __launch_bounds__(256)
void rowhead_kernel(const float* __restrict__ Cpart,
                    const float* __restrict__ b2,
                    const float* __restrict__ W3,
                    const float* __restrict__ b3,
                    const float* __restrict__ sel,
                    const float* __restrict__ top_score,
                    const unsigned* __restrict__ valid,
                    const unsigned* __restrict__ keep,
                    float* __restrict__ out) {
    __shared__ float red[4][4];
    int r = blockIdx.x, t = threadIdx.x;
    int wave = t >> 6, lane = t & 63;
    int c = t * 4;
    const int MN = MAXD * HID;
    float4 s = *(const float4*)&Cpart[(long)r * HID + c];
#pragma unroll
    for (int z = 1; z < SPLITK; ++z) {
        float4 p = *(const float4*)&Cpart[(long)z * MN + (long)r * HID + c];
        s.x += p.x; s.y += p.y; s.z += p.z; s.w += p.w;
    }
    float4 bi = *(const float4*)&b2[c];
    float h[4];
    h[0] = fmaxf(s.x + bi.x, 0.0f);
    h[1] = fmaxf(s.y + bi.y, 0.0f);
    h[2] = fmaxf(s.z + bi.z, 0.0f);
    h[3] = fmaxf(s.w + bi.w, 0.0f);
    float a0 = 0.f, a1 = 0.f, a2 = 0.f, a3 = 0.f;
#pragma unroll
    for (int i = 0; i < 4; ++i) {
        float4 w = *(const float4*)&W3[(c + i) * 4];
        a0 += h[i] * w.x; a1 += h[i] * w.y;
        a2 += h[i] * w.z; a3 += h[i] * w.w;
    }
#pragma unroll
    for (int off = 32; off > 0; off >>= 1) {
        a0 += __shfl_down(a0, off);
        a1 += __shfl_down(a1, off);
        a2 += __shfl_down(a2, off);
        a3 += __shfl_down(a3, off);
    }
    if (lane == 0) {
        red[wave][0] = a0; red[wave][1] = a1;
        red[wave][2] = a2; red[wave][3] = a3;
    }
    __syncthreads();
    if (t == 0) {
        float d0 = red[0][0] + red[1][0] + red[2][0] + red[3][0] + b3[0];
        float d1 = red[0][1] + red[1][1] + red[2][1] + red[3][1] + b3[1];
        float d2 = red[0][2] + red[1][2] + red[2][2] + red[3][2] + b3[2];
        float d3 = red[0][3] + red[1][3] + red[2][3] + red[3][3] + b3[3];
        if (keep[r] != 0u) {
            float4 b = ((const float4*)sel)[r];
            float acx = b.x + 0.5f * b.z;
            float acy = b.y + 0.5f * b.w;
            float cx = acx + d0 * b.z;
            float cy = acy + d1 * b.w;
            float nw = b.z * expf(d2);
            float nh = b.w * expf(d3);
            out[r * 5 + 0] = cx - 0.5f * nw;
            out[r * 5 + 1] = cy - 0.5f * nh;
            out[r * 5 + 2] = nw;
            out[r * 5 + 3] = nh;
            out[r * 5 + 4] = (valid[r] != 0u) ? top_score[r] : 0.0f;
        } else {
            out[r * 5 + 0] = 0.0f;
            out[r * 5 + 1] = 0.0f;
            out[r * 5 + 2] = 0.0f;
            out[r * 5 + 3] = 0.0f;
            out[r * 5 + 4] = 0.0f;
        }
    }
}

// ---------------------------------------------------------------- host
extern "C" void kernel_launch(void* const* d_in, const int* in_sizes, int n_in,
                              void* d_out, int out_size, void* d_ws, size_t ws_size,
                              hipStream_t stream) {
    const float* features = (const float*)d_in[0];
    const float* rpn_obj  = (const float*)d_in[1];
    const float* rpn_reg  = (const float*)d_in[2];
    const float* anchors  = (const float*)d_in[3];
    const float* W1 = (const float*)d_in[4];
    const float* b1 = (const float*)d_in[5];
    const float* W2 = (const float*)d_in[6];
    const float* b2 = (const float*)d_in[7];
    const float* W3 = (const float*)d_in[8];
    const float* b3 = (const float*)d_in[9];
    float* out = (float*)d_out;

    char* ws = (char*)d_ws;
    size_t off = 0;
    auto alloc = [&](size_t bytes) {
        char* p = ws + off;
        off += (bytes + 255) & ~(size_t)255;
        return p;
    };
    unsigned* hist      = (unsigned*)alloc(NBUCK * sizeof(unsigned));
    unsigned long long* bins =
        (unsigned long long*)alloc((size_t)NBUCK * BINCAP * 8);
    float*    sel       = (float*)alloc(MAXD * 4 * sizeof(float));
    float*    top_score = (float*)alloc(MAXD * sizeof(float));
    unsigned* valid     = (unsigned*)alloc(MAXD * sizeof(unsigned));
    unsigned* keep      = (unsigned*)alloc(MAXD * sizeof(unsigned));
    unsigned long long* mask = (unsigned long long*)alloc(MAXD * 8 * 8);
    unsigned short* pooled = (unsigned short*)alloc((size_t)MAXD * FIN * 2);
    unsigned short* W1t = (unsigned short*)alloc((size_t)FIN * HID * 2);
    unsigned short* W2t = (unsigned short*)alloc((size_t)HID * HID * 2);
    unsigned short* h1  = (unsigned short*)alloc((size_t)MAXD * HID * 2);
    float*    Cpart     = (float*)alloc((size_t)SPLITK * MAXD * HID * sizeof(float));
    (void)ws_size; (void)in_sizes; (void)n_in; (void)out_size;

    const int TBLOCKS = (FIN / 32) * (HID / 32) + (HID / 32) * (HID / 32);
    hipMemsetAsync(hist, 0, NBUCK * sizeof(unsigned), stream);
    front_kernel<<<256 + TBLOCKS, 256, 0, stream>>>(rpn_obj, hist, bins,
                                                    W1, W1t, W2, W2t);
    tgs_kernel<<<1, 1024, 0, stream>>>(hist, bins, rpn_reg, anchors,
                                       sel, top_score, valid);
    iou_mask_kernel<<<MAXD, 512, 0, stream>>>(sel, mask);
    nms_scan_kernel<<<1, 64, 0, stream>>>(mask, valid, keep);
    roialign_kernel<<<MAXD * 9, 256, 0, stream>>>(features, sel, pooled);

    const int MN = MAXD * HID;
    mfma_gemm_kernel<<<dim3(HID / 64, MAXD / 64, SPLITK), 256, 0, stream>>>(
        pooled, W1t, Cpart, MAXD, HID, FIN);
    reduce_bias_relu_kernel<<<MN / 4 / 256, 256, 0, stream>>>(
        Cpart, b1, h1, MN, HID);
    mfma_gemm_kernel<<<dim3(HID / 64, MAXD / 64, SPLITK), 256, 0, stream>>>(
        h1, W2t, Cpart, MAXD, HID, HID);
    rowhead_kernel<<<MAXD, 256, 0, stream>>>(Cpart, b2, W3, b3, sel,
                                             top_score, valid, keep, out);
}

// Round 4
// 202.502 us; speedup vs baseline: 1.0705x; 1.0705x over previous
//
#include <hip/hip_runtime.h>
#include <math.h>

#define HFD 128
#define WFD 128
#define DFD 512
#define KA  4
#define NA  (HFD*WFD*KA)      // 65536
#define MAXD 512
#define HID 1024
#define FIN 4608              // 3*3*512
#define CMAX 2048
#define NBUCK 1025
#define BINCAP 64
#define TAUF 0.5f
#define NMS_THR 0.3f
#define SPLITK 4
#define GEMM_BLOCKS (16 * 8 * SPLITK)   // N/64 x M/64 x SPLITK = 512

typedef __bf16 bf16x8 __attribute__((ext_vector_type(8)));
typedef float  floatx4 __attribute__((ext_vector_type(4)));

__device__ __forceinline__ unsigned short f2bf(float x) {
    unsigned u = __float_as_uint(x);
    unsigned r = (u + 0x7FFFu + ((u >> 16) & 1u)) >> 16;   // RNE
    return (unsigned short)r;
}

// ---- grid-wide front: score+bucket-bin (blocks 0..255) + transposes
__global__ __launch_bounds__(256)
void front_kernel(const float* __restrict__ rpn_obj,
                  unsigned* __restrict__ hist,
                  unsigned long long* __restrict__ bins,
                  const float* __restrict__ W1,
                  unsigned short* __restrict__ W1t,
                  const float* __restrict__ W2,
                  unsigned short* __restrict__ W2t) {
    __shared__ float tile[32][33];
    int b = blockIdx.x;
    if (b < 256) {
        int n = b * 256 + threadIdx.x;
        float2 o = ((const float2*)rpn_obj)[n];
        float m  = fmaxf(o.x, o.y);
        float e0 = expf(o.x - m), e1 = expf(o.y - m);
        float s  = e1 / (e0 + e1);
        if (s > TAUF) {
            unsigned bits = __float_as_uint(s);
            unsigned bk = (bits - 0x3F000000u) >> 13;     // 0..1024
            unsigned slot = atomicAdd(&hist[bk], 1u);
            if (slot < BINCAP)
                bins[bk * BINCAP + slot] =
                    ((unsigned long long)bits << 32) |
                    (unsigned long long)(~(unsigned)n);
        }
        return;
    }
    b -= 256;
    const float* W; unsigned short* Wt; int K, N;
    if (b < (FIN / 32) * (HID / 32)) { W = W1; Wt = W1t; K = FIN; N = HID; }
    else { b -= (FIN / 32) * (HID / 32); W = W2; Wt = W2t; K = HID; N = HID; }
    int bn = (b & (N / 32 - 1)) * 32;
    int bk = (b / (N / 32)) * 32;
    int tx = threadIdx.x & 31, ty = threadIdx.x >> 5;     // ty 0..7
#pragma unroll
    for (int r = 0; r < 32; r += 8)
        tile[ty + r][tx] = W[(long)(bk + ty + r) * N + bn + tx];
    __syncthreads();
#pragma unroll
    for (int r = 0; r < 32; r += 8)
        Wt[(long)(bn + ty + r) * K + bk + tx] = f2bf(tile[tx][ty + r]);
}

// ---- single block: threshold + parallel gather + sort + decode
__global__ __launch_bounds__(1024)
void tgs_kernel(const unsigned* __restrict__ hist,
                const unsigned long long* __restrict__ bins,
                const float* __restrict__ rpn_reg,
                const float* __restrict__ anchors,
                float* __restrict__ sel,          // 512 x float4
                float* __restrict__ top_score,    // 512
                unsigned* __restrict__ valid_g) { // 512
    __shared__ unsigned long long keys[CMAX];     // 16 KB
    __shared__ unsigned Hs[NBUCK];                // 4.1 KB
    __shared__ unsigned Ssc[1024];                // 4 KB
    __shared__ unsigned cntS;
    __shared__ unsigned thrS;

    int tid = threadIdx.x;
    int wave = tid >> 6, lane = tid & 63;

    // ---- phase A: load hist, suffix-sum buckets 1..1024, find threshold
    if (tid == 0) cntS = 0u;
    for (int i = tid; i < NBUCK; i += 1024) Hs[i] = hist[i];
    __syncthreads();
    unsigned sv = Hs[tid + 1];                    // thread t <-> bucket t+1
    Ssc[tid] = sv;
    __syncthreads();
    for (int d = 1; d < 1024; d <<= 1) {
        unsigned add = (tid + d < 1024) ? Ssc[tid + d] : 0u;
        __syncthreads();
        Ssc[tid] += add;
        __syncthreads();
    }
    if (tid == 0 && Ssc[0] < MAXD) thrS = 0u;
    {
        unsigned Scur = Ssc[tid];
        unsigned Snxt = (tid == 1023) ? 0u : Ssc[tid + 1];
        if (Scur >= MAXD && Snxt < MAXD) thrS = (unsigned)(tid + 1);
    }
    __syncthreads();
    unsigned thr = thrS;

    // ---- phase B: wave-per-bucket PARALLEL gather (lane i -> slot i)
    for (int b = (int)thr + wave; b < NBUCK; b += 16) {
        unsigned c = Hs[b]; if (c > BINCAP) c = BINCAP;
        unsigned base = 0;
        if (lane == 0 && c > 0) base = atomicAdd(&cntS, c);
        base = __shfl(base, 0);
        if (c > 0 && lane < c && base + lane < CMAX)
            keys[base + lane] = bins[(long)b * BINCAP + lane];
    }
    __syncthreads();
    unsigned cnt = cntS; if (cnt > CMAX) cnt = CMAX;
    int SN = (cnt <= 1024) ? 1024 : CMAX;
    for (int i = tid; i < SN; i += 1024)
        if (i >= (int)cnt) keys[i] = 0ULL;
    __syncthreads();

    // ---- phase C: bitonic sort descending over SN
    for (int k = 2; k <= SN; k <<= 1) {
        for (int j = k >> 1; j > 0; j >>= 1) {
            for (int i = tid; i < SN; i += 1024) {
                int ixj = i ^ j;
                if (ixj > i) {
                    unsigned long long a = keys[i], b = keys[ixj];
                    bool up = ((i & k) == 0);
                    if ((a < b) == up) { keys[i] = b; keys[ixj] = a; }
                }
            }
            __syncthreads();
        }
    }

    // ---- phase D: decode top-512 boxes (same fp32 formulas)
    if (tid < MAXD) {
        unsigned long long e = keys[tid];
        unsigned sbits = (unsigned)(e >> 32);
        bool v = (sbits != 0u);
        unsigned idx = v ? (unsigned)(~(unsigned)e) : 0u;
        int cell = idx >> 2, kk = idx & 3;
        float4 rg = *(const float4*)&rpn_reg[cell * 16 + 4 * kk];
        float4 an = *(const float4*)&anchors[idx * 4];
        float acx = an.x + an.z * 0.5f;
        float acy = an.y + an.w * 0.5f;
        float cx = acx + rg.x * an.z;
        float cy = acy + rg.y * an.w;
        float w  = an.z * expf(rg.z);
        float h  = an.w * expf(rg.w);
        ((float4*)sel)[tid] = make_float4(cx - 0.5f * w, cy - 0.5f * h, w, h);
        top_score[tid] = v ? __uint_as_float(sbits) : 0.0f;
        valid_g[tid]   = v ? 1u : 0u;
    }
}

// ---- ROI align (blocks 0..4607, tile-split 9/ROI) + IoU bitmask
//      (blocks 4608..5119, one row each). Both depend only on sel.
__global__ __launch_bounds__(256)
void roialign_iou_kernel(const float* __restrict__ feat,
                         const float* __restrict__ sel,
                         unsigned short* __restrict__ pooled,
                         unsigned long long* __restrict__ mask) {
    int blk = blockIdx.x;
    if (blk >= MAXD * 9) {
        // -------- IoU row: thread t covers cols t and t+256
        int i = blk - MAXD * 9;
        int t = threadIdx.x, wv = t >> 6, lane = t & 63;
        float4 bi = ((const float4*)sel)[i];
        float x2i = bi.x + bi.z, y2i = bi.y + bi.w;
        float ai = bi.z * bi.w;
#pragma unroll
        for (int h = 0; h < 2; ++h) {
            int j = h * 256 + wv * 64 + lane;
            float4 bj = ((const float4*)sel)[j];
            float x2j = bj.x + bj.z, y2j = bj.y + bj.w;
            float aj = bj.z * bj.w;
            float ix = fmaxf(0.0f, fminf(x2i, x2j) - fmaxf(bi.x, bj.x));
            float iy = fmaxf(0.0f, fminf(y2i, y2j) - fmaxf(bi.y, bj.y));
            float inter = ix * iy;
            float iou = inter / (ai + aj - inter + 1e-8f);
            unsigned long long bal = __ballot(iou > NMS_THR);
            if (lane == 0) mask[i * 8 + h * 4 + wv] = bal;
        }
        return;
    }
    // -------- ROI align tile
    int mrow = blk / 9;
    int tile = blk - mrow * 9;        // (p>>1)*3 + (q>>1)
    int tp = tile / 3, tq = tile - tp * 3;
    int c = threadIdx.x;              // channels c and c+256
    float4 b = ((const float4*)sel)[mrow];
    float vmax0 = -INFINITY, vmax1 = -INFINITY;
#pragma unroll
    for (int dp = 0; dp < 2; ++dp) {
        int p = tp * 2 + dp;
        float fy = (b.y + ((float)p + 0.5f) / 6.0f * b.w) / 16.0f - 0.5f;
        fy = fminf(fmaxf(fy, 0.0f), 127.0f);
        int y0 = (int)floorf(fy);
        int y1 = min(y0 + 1, 127);
        float wy = fy - (float)y0;
#pragma unroll
        for (int dq = 0; dq < 2; ++dq) {
            int q = tq * 2 + dq;
            float fx = (b.x + ((float)q + 0.5f) / 6.0f * b.z) / 16.0f - 0.5f;
            fx = fminf(fmaxf(fx, 0.0f), 127.0f);
            int x0 = (int)floorf(fx);
            int x1 = min(x0 + 1, 127);
            float wx = fx - (float)x0;
            const float* f00 = feat + (y0 * WFD + x0) * DFD;
            const float* f01 = feat + (y0 * WFD + x1) * DFD;
            const float* f10 = feat + (y1 * WFD + x0) * DFD;
            const float* f11 = feat + (y1 * WFD + x1) * DFD;
            float w00 = (1.0f - wy) * (1.0f - wx);
            float w01 = (1.0f - wy) * wx;
            float w10 = wy * (1.0f - wx);
            float w11 = wy * wx;
            float v0 = f00[c] * w00 + f01[c] * w01 + f10[c] * w10 + f11[c] * w11;
            float v1 = f00[c + 256] * w00 + f01[c + 256] * w01 +
                       f10[c + 256] * w10 + f11[c + 256] * w11;
            vmax0 = fmaxf(vmax0, v0);
            vmax1 = fmaxf(vmax1, v1);
        }
    }
    pooled[mrow * FIN + tile * DFD + c] = f2bf(vmax0);
    pooled[mrow * FIN + tile * DFD + c + 256] = f2bf(vmax1);
}

// --------------------------------------- bf16 MFMA GEMM with split-K
// Flat 1-D grid (512 blocks). If mask != nullptr, one extra tail block
// runs the NMS column-owner scan concurrently (keep[] is only consumed
// by rowhead, 3 launches later).
#define LDK 72
__global__ __launch_bounds__(256)
void mfma_gemm_kernel(const unsigned short* __restrict__ A,
                      const unsigned short* __restrict__ Bt,
                      float* __restrict__ Cpart,
                      int K,
                      const unsigned long long* __restrict__ mask,
                      const unsigned* __restrict__ valid,
                      unsigned* __restrict__ keep) {
    int blk = blockIdx.x;
    if (blk >= GEMM_BLOCKS) {
        // -------- NMS scan tail block (wave 0 only; no barriers here)
        int lane = threadIdx.x;
        if (lane >= 64) return;
        unsigned long long vb[8];
#pragma unroll
        for (int g = 0; g < 8; ++g)
            vb[g] = __ballot(valid[g * 64 + lane] != 0u);
        unsigned long long cw[8], cwn[8];
#pragma unroll
        for (int g = 0; g < 8; ++g)
            cw[g] = mask[(g * 64 + lane) * 8 + 0];
        unsigned supp8 = 0u;
#pragma unroll
        for (int G = 0; G < 8; ++G) {
            if (G < 7) {
#pragma unroll
                for (int g = 0; g < 8; ++g)
                    cwn[g] = mask[(g * 64 + lane) * 8 + (G + 1)];
            }
            unsigned long long kg = 0ULL;
            unsigned long long vbG = vb[G];
            for (int b = 0; b < 64; ++b) {
                unsigned long long sg = __ballot((supp8 >> G) & 1u);
                unsigned long long bi = 1ULL << b;
                if (((vbG & bi) != 0ULL) && ((sg & bi) == 0ULL)) {  // uniform
                    kg |= bi;
                    unsigned nb = 0u;
#pragma unroll
                    for (int g = 0; g < 8; ++g)
                        nb |= (unsigned)((cw[g] >> b) & 1ULL) << g;
                    supp8 |= nb;
                }
            }
            keep[G * 64 + lane] = (unsigned)((kg >> lane) & 1ULL);
#pragma unroll
            for (int g = 0; g < 8; ++g) cw[g] = cwn[g];
        }
        return;
    }

    __shared__ unsigned short As[64 * LDK];
    __shared__ unsigned short Bs[64 * LDK];
    int tid = threadIdx.x;
    int wave = tid >> 6, lane = tid & 63;
    int bz = blk >> 7;            // / (16*8)
    int rem = blk & 127;
    int bm = (rem >> 4) * 64, bn = (rem & 15) * 64;
    int KC = K / SPLITK;
    int ks = bz * KC;

    floatx4 acc[4] = {};
    int lr = tid >> 2;            // 0..63  staging row
    int lk = (tid & 3) << 4;      // 0,16,32,48  staging k-offset (shorts)
    int frow = lane & 15, quad = lane >> 4;

    const unsigned short* Ap = A + (long)(bm + lr) * K + lk;
    const unsigned short* Bp = Bt + (long)(bn + lr) * K + lk;

    for (int k0 = ks; k0 < ks + KC; k0 += 64) {
        uint4 a0 = *(const uint4*)(Ap + k0);
        uint4 a1 = *(const uint4*)(Ap + k0 + 8);
        uint4 b0 = *(const uint4*)(Bp + k0);
        uint4 b1 = *(const uint4*)(Bp + k0 + 8);
        *(uint4*)&As[lr * LDK + lk] = a0;
        *(uint4*)&As[lr * LDK + lk + 8] = a1;
        *(uint4*)&Bs[lr * LDK + lk] = b0;
        *(uint4*)&Bs[lr * LDK + lk + 8] = b1;
        __syncthreads();
        bf16x8 af0 = *(const bf16x8*)&As[(wave * 16 + frow) * LDK + quad * 8];
        bf16x8 af1 = *(const bf16x8*)&As[(wave * 16 + frow) * LDK + 32 + quad * 8];
#pragma unroll
        for (int t = 0; t < 4; ++t) {
            bf16x8 b0v = *(const bf16x8*)&Bs[(t * 16 + frow) * LDK + quad * 8];
            bf16x8 b1v = *(const bf16x8*)&Bs[(t * 16 + frow) * LDK + 32 + quad * 8];
            acc[t] = __builtin_amdgcn_mfma_f32_16x16x32_bf16(af0, b0v, acc[t], 0, 0, 0);
            acc[t] = __builtin_amdgcn_mfma_f32_16x16x32_bf16(af1, b1v, acc[t], 0, 0, 0);
        }
        __syncthreads();
    }

    float* Cp = Cpart + (long)bz * MAXD * HID;
#pragma unroll
    for (int t = 0; t < 4; ++t) {
#pragma unroll
        for (int r = 0; r < 4; ++r) {
            int m = bm + wave * 16 + quad * 4 + r;
            int n = bn + t * 16 + frow;
            Cp[(long)m * HID + n] = acc[t][r];
        }
    }
}

// --------------------- split-K reduce + bias + relu -> bf16
__global__ __launch_bounds__(256)
void reduce_bias_relu_kernel(const float* __restrict__ Cpart,
                             const float* __restrict__ bias,
                             unsigned short* __restrict__ out_bf,
                             int MN, int N) {
    int i4 = (blockIdx.x * blockDim.x + threadIdx.x) * 4;
    if (i4 >= MN) return;
    float4 s = *(const float4*)&Cpart[i4];
#pragma unroll
    for (int z = 1; z < SPLITK; ++z) {
        float4 p = *(const float4*)&Cpart[(long)z * MN + i4];
        s.x += p.x; s.y += p.y; s.z += p.z; s.w += p.w;
    }
    int n = i4 & (N - 1);
    float4 bi = *(const float4*)&bias[n];
    s.x = fmaxf(s.x + bi.x, 0.0f);
    s.y = fmaxf(s.y + bi.y, 0.0f);
    s.z = fmaxf(s.z + bi.z, 0.0f);
    s.w = fmaxf(s.w + bi.w, 0.0f);
    uint2 o;
    o.x = (unsigned)f2bf(s.x) | ((unsigned)f2bf(s.y) << 16);
    o.y = (unsigned)f2bf(s.z) | ((unsigned)f2bf(s.w) << 16);
    *(uint2*)&out_bf[i4] = o;
}

// --- fused: split-K reduce (GEMM2) + bias2 + relu + W3 dot + epilogue
__global__ __launch_bounds__(256)
void rowhead_kernel(const float* __restrict__ Cpart,
                    const float* __restrict__ b2,
                    const float* __restrict__ W3,
                    const float* __restrict__ b3,
                    const float* __restrict__ sel,
                    const float* __restrict__ top_score,
                    const unsigned* __restrict__ valid,
                    const unsigned* __restrict__ keep,
                    float* __restrict__ out) {
    __shared__ float red[4][4];
    int r = blockIdx.x, t = threadIdx.x;
    int wave = t >> 6, lane = t & 63;
    int c = t * 4;
    const int MN = MAXD * HID;
    float4 s = *(const float4*)&Cpart[(long)r * HID + c];
#pragma unroll
    for (int z = 1; z < SPLITK; ++z) {
        float4 p = *(const float4*)&Cpart[(long)z * MN + (long)r * HID + c];
        s.x += p.x; s.y += p.y; s.z += p.z; s.w += p.w;
    }
    float4 bi = *(const float4*)&b2[c];
    float h[4];
    h[0] = fmaxf(s.x + bi.x, 0.0f);
    h[1] = fmaxf(s.y + bi.y, 0.0f);
    h[2] = fmaxf(s.z + bi.z, 0.0f);
    h[3] = fmaxf(s.w + bi.w, 0.0f);
    float a0 = 0.f, a1 = 0.f, a2 = 0.f, a3 = 0.f;
#pragma unroll
    for (int i = 0; i < 4; ++i) {
        float4 w = *(const float4*)&W3[(c + i) * 4];
        a0 += h[i] * w.x; a1 += h[i] * w.y;
        a2 += h[i] * w.z; a3 += h[i] * w.w;
    }
#pragma unroll
    for (int off = 32; off > 0; off >>= 1) {
        a0 += __shfl_down(a0, off);
        a1 += __shfl_down(a1, off);
        a2 += __shfl_down(a2, off);
        a3 += __shfl_down(a3, off);
    }
    if (lane == 0) {
        red[wave][0] = a0; red[wave][1] = a1;
        red[wave][2] = a2; red[wave][3] = a3;
    }
    __syncthreads();
    if (t == 0) {
        float d0 = red[0][0] + red[1][0] + red[2][0] + red[3][0] + b3[0];
        float d1 = red[0][1] + red[1][1] + red[2][1] + red[3][1] + b3[1];
        float d2 = red[0][2] + red[1][2] + red[2][2] + red[3][2] + b3[2];
        float d3 = red[0][3] + red[1][3] + red[2][3] + red[3][3] + b3[3];
        if (keep[r] != 0u) {
            float4 b = ((const float4*)sel)[r];
            float acx = b.x + 0.5f * b.z;
            float acy = b.y + 0.5f * b.w;
            float cx = acx + d0 * b.z;
            float cy = acy + d1 * b.w;
            float nw = b.z * expf(d2);
            float nh = b.w * expf(d3);
            out[r * 5 + 0] = cx - 0.5f * nw;
            out[r * 5 + 1] = cy - 0.5f * nh;
            out[r * 5 + 2] = nw;
            out[r * 5 + 3] = nh;
            out[r * 5 + 4] = (valid[r] != 0u) ? top_score[r] : 0.0f;
        } else {
            out[r * 5 + 0] = 0.0f;
            out[r * 5 + 1] = 0.0f;
            out[r * 5 + 2] = 0.0f;
            out[r * 5 + 3] = 0.0f;
            out[r * 5 + 4] = 0.0f;
        }
    }
}

// ---------------------------------------------------------------- host
extern "C" void kernel_launch(void* const* d_in, const int* in_sizes, int n_in,
                              void* d_out, int out_size, void* d_ws, size_t ws_size,
                              hipStream_t stream) {
    const float* features = (const float*)d_in[0];
    const float* rpn_obj  = (const float*)d_in[1];
    const float* rpn_reg  = (const float*)d_in[2];
    const float* anchors  = (const float*)d_in[3];
    const float* W1 = (const float*)d_in[4];
    const float* b1 = (const float*)d_in[5];
    const float* W2 = (const float*)d_in[6];
    const float* b2 = (const float*)d_in[7];
    const float* W3 = (const float*)d_in[8];
    const float* b3 = (const float*)d_in[9];
    float* out = (float*)d_out;

    char* ws = (char*)d_ws;
    size_t off = 0;
    auto alloc = [&](size_t bytes) {
        char* p = ws + off;
        off += (bytes + 255) & ~(size_t)255;
        return p;
    };
    unsigned* hist      = (unsigned*)alloc(NBUCK * sizeof(unsigned));
    unsigned long long* bins =
        (unsigned long long*)alloc((size_t)NBUCK * BINCAP * 8);
    float*    sel       = (float*)alloc(MAXD * 4 * sizeof(float));
    float*    top_score = (float*)alloc(MAXD * sizeof(float));
    unsigned* valid     = (unsigned*)alloc(MAXD * sizeof(unsigned));
    unsigned* keep      = (unsigned*)alloc(MAXD * sizeof(unsigned));
    unsigned long long* mask = (unsigned long long*)alloc(MAXD * 8 * 8);
    unsigned short* pooled = (unsigned short*)alloc((size_t)MAXD * FIN * 2);
    unsigned short* W1t = (unsigned short*)alloc((size_t)FIN * HID * 2);
    unsigned short* W2t = (unsigned short*)alloc((size_t)HID * HID * 2);
    unsigned short* h1  = (unsigned short*)alloc((size_t)MAXD * HID * 2);
    float*    Cpart     = (float*)alloc((size_t)SPLITK * MAXD * HID * sizeof(float));
    (void)ws_size; (void)in_sizes; (void)n_in; (void)out_size;

    const int TBLOCKS = (FIN / 32) * (HID / 32) + (HID / 32) * (HID / 32);
    hipMemsetAsync(hist, 0, NBUCK * sizeof(unsigned), stream);
    front_kernel<<<256 + TBLOCKS, 256, 0, stream>>>(rpn_obj, hist, bins,
                                                    W1, W1t, W2, W2t);
    tgs_kernel<<<1, 1024, 0, stream>>>(hist, bins, rpn_reg, anchors,
                                       sel, top_score, valid);
    // roialign (4608 blocks) + iou rows (512 blocks), both need only sel
    roialign_iou_kernel<<<MAXD * 9 + MAXD, 256, 0, stream>>>(features, sel,
                                                             pooled, mask);
    const int MN = MAXD * HID;
    // GEMM1 (512 blocks) + 1 tail block running the NMS scan concurrently
    mfma_gemm_kernel<<<GEMM_BLOCKS + 1, 256, 0, stream>>>(
        pooled, W1t, Cpart, FIN, mask, valid, keep);
    reduce_bias_relu_kernel<<<MN / 4 / 256, 256, 0, stream>>>(
        Cpart, b1, h1, MN, HID);
    mfma_gemm_kernel<<<GEMM_BLOCKS, 256, 0, stream>>>(
        h1, W2t, Cpart, HID, nullptr, nullptr, nullptr);
    rowhead_kernel<<<MAXD, 256, 0, stream>>>(Cpart, b2, W3, b3, sel,
                                             top_score, valid, keep, out);
}

// Round 5
// 180.110 us; speedup vs baseline: 1.2036x; 1.1243x over previous
//
#include <hip/hip_runtime.h>
#include <math.h>

#define HFD 128
#define WFD 128
#define DFD 512
#define KA  4
#define NA  (HFD*WFD*KA)      // 65536
#define MAXD 512
#define HID 1024
#define FIN 4608              // 3*3*512
#define CMAX 2048
#define NBUCK 1025
#define BINCAP 64
#define TAUF 0.5f
#define NMS_THR 0.3f
#define SPLITK 4
#define GEMM_BLOCKS (16 * 8 * SPLITK)   // N/64 x M/64 x SPLITK = 512

typedef __bf16 bf16x8 __attribute__((ext_vector_type(8)));
typedef float  floatx4 __attribute__((ext_vector_type(4)));

__device__ __forceinline__ unsigned short f2bf(float x) {
    unsigned u = __float_as_uint(x);
    unsigned r = (u + 0x7FFFu + ((u >> 16) & 1u)) >> 16;   // RNE
    return (unsigned short)r;
}

__device__ __forceinline__ unsigned long long rdlane64(unsigned long long v, int b) {
    unsigned lo = (unsigned)__builtin_amdgcn_readlane((int)(unsigned)v, b);
    unsigned hi = (unsigned)__builtin_amdgcn_readlane((int)(unsigned)(v >> 32), b);
    return ((unsigned long long)hi << 32) | lo;
}

// ---- grid-wide front: score+bucket-bin (blocks 0..255) + transposes
__global__ __launch_bounds__(256)
void front_kernel(const float* __restrict__ rpn_obj,
                  unsigned* __restrict__ hist,
                  unsigned long long* __restrict__ bins,
                  const float* __restrict__ W1,
                  unsigned short* __restrict__ W1t,
                  const float* __restrict__ W2,
                  unsigned short* __restrict__ W2t) {
    __shared__ float tile[32][33];
    int b = blockIdx.x;
    if (b < 256) {
        int n = b * 256 + threadIdx.x;
        float2 o = ((const float2*)rpn_obj)[n];
        float m  = fmaxf(o.x, o.y);
        float e0 = expf(o.x - m), e1 = expf(o.y - m);
        float s  = e1 / (e0 + e1);
        if (s > TAUF) {
            unsigned bits = __float_as_uint(s);
            unsigned bk = (bits - 0x3F000000u) >> 13;     // 0..1024
            unsigned slot = atomicAdd(&hist[bk], 1u);
            if (slot < BINCAP)
                bins[bk * BINCAP + slot] =
                    ((unsigned long long)bits << 32) |
                    (unsigned long long)(~(unsigned)n);
        }
        return;
    }
    b -= 256;
    const float* W; unsigned short* Wt; int K, N;
    if (b < (FIN / 32) * (HID / 32)) { W = W1; Wt = W1t; K = FIN; N = HID; }
    else { b -= (FIN / 32) * (HID / 32); W = W2; Wt = W2t; K = HID; N = HID; }
    int bn = (b & (N / 32 - 1)) * 32;
    int bk = (b / (N / 32)) * 32;
    int tx = threadIdx.x & 31, ty = threadIdx.x >> 5;     // ty 0..7
#pragma unroll
    for (int r = 0; r < 32; r += 8)
        tile[ty + r][tx] = W[(long)(bk + ty + r) * N + bn + tx];
    __syncthreads();
#pragma unroll
    for (int r = 0; r < 32; r += 8)
        Wt[(long)(bn + ty + r) * K + bk + tx] = f2bf(tile[tx][ty + r]);
}

// ---- single block: threshold + parallel gather + sort + decode
__global__ __launch_bounds__(1024)
void tgs_kernel(const unsigned* __restrict__ hist,
                const unsigned long long* __restrict__ bins,
                const float* __restrict__ rpn_reg,
                const float* __restrict__ anchors,
                float* __restrict__ sel,          // 512 x float4
                float* __restrict__ top_score,    // 512
                unsigned* __restrict__ valid_g) { // 512
    __shared__ unsigned long long keys[CMAX];     // 16 KB
    __shared__ unsigned Hs[NBUCK];                // 4.1 KB
    __shared__ unsigned Ssc[1024];                // 4 KB
    __shared__ unsigned cntS;
    __shared__ unsigned thrS;

    int tid = threadIdx.x;
    int wave = tid >> 6, lane = tid & 63;

    // ---- phase A: load hist, suffix-sum buckets 1..1024, find threshold
    if (tid == 0) cntS = 0u;
    for (int i = tid; i < NBUCK; i += 1024) Hs[i] = hist[i];
    __syncthreads();
    unsigned sv = Hs[tid + 1];                    // thread t <-> bucket t+1
    Ssc[tid] = sv;
    __syncthreads();
    for (int d = 1; d < 1024; d <<= 1) {
        unsigned add = (tid + d < 1024) ? Ssc[tid + d] : 0u;
        __syncthreads();
        Ssc[tid] += add;
        __syncthreads();
    }
    if (tid == 0 && Ssc[0] < MAXD) thrS = 0u;
    {
        unsigned Scur = Ssc[tid];
        unsigned Snxt = (tid == 1023) ? 0u : Ssc[tid + 1];
        if (Scur >= MAXD && Snxt < MAXD) thrS = (unsigned)(tid + 1);
    }
    __syncthreads();
    unsigned thr = thrS;

    // ---- phase B: wave-per-bucket PARALLEL gather (lane i -> slot i)
    for (int b = (int)thr + wave; b < NBUCK; b += 16) {
        unsigned c = Hs[b]; if (c > BINCAP) c = BINCAP;
        unsigned base = 0;
        if (lane == 0 && c > 0) base = atomicAdd(&cntS, c);
        base = __shfl(base, 0);
        if (c > 0 && lane < c && base + lane < CMAX)
            keys[base + lane] = bins[(long)b * BINCAP + lane];
    }
    __syncthreads();
    unsigned cnt = cntS; if (cnt > CMAX) cnt = CMAX;
    int SN = (cnt <= 1024) ? 1024 : CMAX;
    for (int i = tid; i < SN; i += 1024)
        if (i >= (int)cnt) keys[i] = 0ULL;
    __syncthreads();

    // ---- phase C: bitonic sort descending over SN
    for (int k = 2; k <= SN; k <<= 1) {
        for (int j = k >> 1; j > 0; j >>= 1) {
            for (int i = tid; i < SN; i += 1024) {
                int ixj = i ^ j;
                if (ixj > i) {
                    unsigned long long a = keys[i], b = keys[ixj];
                    bool up = ((i & k) == 0);
                    if ((a < b) == up) { keys[i] = b; keys[ixj] = a; }
                }
            }
            __syncthreads();
        }
    }

    // ---- phase D: decode top-512 boxes (same fp32 formulas)
    if (tid < MAXD) {
        unsigned long long e = keys[tid];
        unsigned sbits = (unsigned)(e >> 32);
        bool v = (sbits != 0u);
        unsigned idx = v ? (unsigned)(~(unsigned)e) : 0u;
        int cell = idx >> 2, kk = idx & 3;
        float4 rg = *(const float4*)&rpn_reg[cell * 16 + 4 * kk];
        float4 an = *(const float4*)&anchors[idx * 4];
        float acx = an.x + an.z * 0.5f;
        float acy = an.y + an.w * 0.5f;
        float cx = acx + rg.x * an.z;
        float cy = acy + rg.y * an.w;
        float w  = an.z * expf(rg.z);
        float h  = an.w * expf(rg.w);
        ((float4*)sel)[tid] = make_float4(cx - 0.5f * w, cy - 0.5f * h, w, h);
        top_score[tid] = v ? __uint_as_float(sbits) : 0.0f;
        valid_g[tid]   = v ? 1u : 0u;
    }
}

// ---- ROI align (blocks 0..4607, tile-split 9/ROI) + IoU bitmask
//      (blocks 4608..5119, one row each). Both depend only on sel.
__global__ __launch_bounds__(256)
void roialign_iou_kernel(const float* __restrict__ feat,
                         const float* __restrict__ sel,
                         unsigned short* __restrict__ pooled,
                         unsigned long long* __restrict__ mask) {
    int blk = blockIdx.x;
    if (blk >= MAXD * 9) {
        // -------- IoU row: thread t covers cols t and t+256
        int i = blk - MAXD * 9;
        int t = threadIdx.x, wv = t >> 6, lane = t & 63;
        float4 bi = ((const float4*)sel)[i];
        float x2i = bi.x + bi.z, y2i = bi.y + bi.w;
        float ai = bi.z * bi.w;
#pragma unroll
        for (int h = 0; h < 2; ++h) {
            int j = h * 256 + wv * 64 + lane;
            float4 bj = ((const float4*)sel)[j];
            float x2j = bj.x + bj.z, y2j = bj.y + bj.w;
            float aj = bj.z * bj.w;
            float ix = fmaxf(0.0f, fminf(x2i, x2j) - fmaxf(bi.x, bj.x));
            float iy = fmaxf(0.0f, fminf(y2i, y2j) - fmaxf(bi.y, bj.y));
            float inter = ix * iy;
            float iou = inter / (ai + aj - inter + 1e-8f);
            unsigned long long bal = __ballot(iou > NMS_THR);
            if (lane == 0) mask[i * 8 + h * 4 + wv] = bal;
        }
        return;
    }
    // -------- ROI align tile
    int mrow = blk / 9;
    int tile = blk - mrow * 9;        // (p>>1)*3 + (q>>1)
    int tp = tile / 3, tq = tile - tp * 3;
    int c = threadIdx.x;              // channels c and c+256
    float4 b = ((const float4*)sel)[mrow];
    float vmax0 = -INFINITY, vmax1 = -INFINITY;
#pragma unroll
    for (int dp = 0; dp < 2; ++dp) {
        int p = tp * 2 + dp;
        float fy = (b.y + ((float)p + 0.5f) / 6.0f * b.w) / 16.0f - 0.5f;
        fy = fminf(fmaxf(fy, 0.0f), 127.0f);
        int y0 = (int)floorf(fy);
        int y1 = min(y0 + 1, 127);
        float wy = fy - (float)y0;
#pragma unroll
        for (int dq = 0; dq < 2; ++dq) {
            int q = tq * 2 + dq;
            float fx = (b.x + ((float)q + 0.5f) / 6.0f * b.z) / 16.0f - 0.5f;
            fx = fminf(fmaxf(fx, 0.0f), 127.0f);
            int x0 = (int)floorf(fx);
            int x1 = min(x0 + 1, 127);
            float wx = fx - (float)x0;
            const float* f00 = feat + (y0 * WFD + x0) * DFD;
            const float* f01 = feat + (y0 * WFD + x1) * DFD;
            const float* f10 = feat + (y1 * WFD + x0) * DFD;
            const float* f11 = feat + (y1 * WFD + x1) * DFD;
            float w00 = (1.0f - wy) * (1.0f - wx);
            float w01 = (1.0f - wy) * wx;
            float w10 = wy * (1.0f - wx);
            float w11 = wy * wx;
            float v0 = f00[c] * w00 + f01[c] * w01 + f10[c] * w10 + f11[c] * w11;
            float v1 = f00[c + 256] * w00 + f01[c + 256] * w01 +
                       f10[c + 256] * w10 + f11[c + 256] * w11;
            vmax0 = fmaxf(vmax0, v0);
            vmax1 = fmaxf(vmax1, v1);
        }
    }
    pooled[mrow * FIN + tile * DFD + c] = f2bf(vmax0);
    pooled[mrow * FIN + tile * DFD + c + 256] = f2bf(vmax1);
}

// --------------------------------------- bf16 MFMA GEMM with split-K
// Flat 1-D grid (512 blocks). If mask != nullptr, one extra tail block
// runs the NMS scan concurrently (keep[] consumed by rowhead, 3
// launches later).
// NMS tail: per-KEPT-box scalar chain. supp8 bit g = column (g,lane)
// suppressed by a kept box from an earlier group. Per group: 1 ballot,
// then ff1-driven closure over a wave-uniform 64-bit alive mask; each
// kept box's intra-group row comes from v_readlane of cw[G] (registers,
// no memory on the chain). Suppressed boxes cost zero iterations.
#define LDK 72
__global__ __launch_bounds__(256)
void mfma_gemm_kernel(const unsigned short* __restrict__ A,
                      const unsigned short* __restrict__ Bt,
                      float* __restrict__ Cpart,
                      int K,
                      const unsigned long long* __restrict__ mask,
                      const unsigned* __restrict__ valid,
                      unsigned* __restrict__ keep) {
    int blk = blockIdx.x;
    if (blk >= GEMM_BLOCKS) {
        int lane = threadIdx.x;
        if (lane >= 64) return;
        unsigned long long vb[8];
#pragma unroll
        for (int g = 0; g < 8; ++g)
            vb[g] = __ballot(valid[g * 64 + lane] != 0u);
        // cw[g] = mask[(g*64+lane)*8 + G]: bit b says kept box (G,b)
        // suppresses column (g,lane). Loaded per-G, prefetched one ahead.
        unsigned long long cw[8], cwn[8];
#pragma unroll
        for (int g = 0; g < 8; ++g)
            cw[g] = mask[(g * 64 + lane) * 8 + 0];
        unsigned supp8 = 0u;
#pragma unroll
        for (int G = 0; G < 8; ++G) {
            if (G < 7) {
#pragma unroll
                for (int g = 0; g < 8; ++g)
                    cwn[g] = mask[(g * 64 + lane) * 8 + (G + 1)];
            }
            unsigned long long alive =
                vb[G] & ~__ballot((supp8 >> G) & 1u);
            unsigned long long Kw = 0ULL;
            while (alive) {                       // wave-uniform scalar loop
                int b = __builtin_ctzll(alive);
                Kw |= 1ULL << b;
                unsigned long long row = rdlane64(cw[G], b); // intra row of b
                alive &= ~row;                    // suppressed never iterate
                alive &= ~(1ULL << b);            // self (diag is 1 anyway)
            }
            keep[G * 64 + lane] = (unsigned)((Kw >> lane) & 1ULL);
#pragma unroll
            for (int g = 0; g < 8; ++g) {
                supp8 |= ((cw[g] & Kw) != 0ULL ? 1u : 0u) << g;
                cw[g] = cwn[g];
            }
        }
        return;
    }

    __shared__ unsigned short As[64 * LDK];
    __shared__ unsigned short Bs[64 * LDK];
    int tid = threadIdx.x;
    int wave = tid >> 6, lane = tid & 63;
    int bz = blk >> 7;            // / (16*8)
    int rem = blk & 127;
    int bm = (rem >> 4) * 64, bn = (rem & 15) * 64;
    int KC = K / SPLITK;
    int ks = bz * KC;

    floatx4 acc[4] = {};
    int lr = tid >> 2;            // 0..63  staging row
    int lk = (tid & 3) << 4;      // 0,16,32,48  staging k-offset (shorts)
    int frow = lane & 15, quad = lane >> 4;

    const unsigned short* Ap = A + (long)(bm + lr) * K + lk;
    const unsigned short* Bp = Bt + (long)(bn + lr) * K + lk;

    for (int k0 = ks; k0 < ks + KC; k0 += 64) {
        uint4 a0 = *(const uint4*)(Ap + k0);
        uint4 a1 = *(const uint4*)(Ap + k0 + 8);
        uint4 b0 = *(const uint4*)(Bp + k0);
        uint4 b1 = *(const uint4*)(Bp + k0 + 8);
        *(uint4*)&As[lr * LDK + lk] = a0;
        *(uint4*)&As[lr * LDK + lk + 8] = a1;
        *(uint4*)&Bs[lr * LDK + lk] = b0;
        *(uint4*)&Bs[lr * LDK + lk + 8] = b1;
        __syncthreads();
        bf16x8 af0 = *(const bf16x8*)&As[(wave * 16 + frow) * LDK + quad * 8];
        bf16x8 af1 = *(const bf16x8*)&As[(wave * 16 + frow) * LDK + 32 + quad * 8];
#pragma unroll
        for (int t = 0; t < 4; ++t) {
            bf16x8 b0v = *(const bf16x8*)&Bs[(t * 16 + frow) * LDK + quad * 8];
            bf16x8 b1v = *(const bf16x8*)&Bs[(t * 16 + frow) * LDK + 32 + quad * 8];
            acc[t] = __builtin_amdgcn_mfma_f32_16x16x32_bf16(af0, b0v, acc[t], 0, 0, 0);
            acc[t] = __builtin_amdgcn_mfma_f32_16x16x32_bf16(af1, b1v, acc[t], 0, 0, 0);
        }
        __syncthreads();
    }

    float* Cp = Cpart + (long)bz * MAXD * HID;
#pragma unroll
    for (int t = 0; t < 4; ++t) {
#pragma unroll
        for (int r = 0; r < 4; ++r) {
            int m = bm + wave * 16 + quad * 4 + r;
            int n = bn + t * 16 + frow;
            Cp[(long)m * HID + n] = acc[t][r];
        }
    }
}

// --------------------- split-K reduce + bias + relu -> bf16
__global__ __launch_bounds__(256)
void reduce_bias_relu_kernel(const float* __restrict__ Cpart,
                             const float* __restrict__ bias,
                             unsigned short* __restrict__ out_bf,
                             int MN, int N) {
    int i4 = (blockIdx.x * blockDim.x + threadIdx.x) * 4;
    if (i4 >= MN) return;
    float4 s = *(const float4*)&Cpart[i4];
#pragma unroll
    for (int z = 1; z < SPLITK; ++z) {
        float4 p = *(const float4*)&Cpart[(long)z * MN + i4];
        s.x += p.x; s.y += p.y; s.z += p.z; s.w += p.w;
    }
    int n = i4 & (N - 1);
    float4 bi = *(const float4*)&bias[n];
    s.x = fmaxf(s.x + bi.x, 0.0f);
    s.y = fmaxf(s.y + bi.y, 0.0f);
    s.z = fmaxf(s.z + bi.z, 0.0f);
    s.w = fmaxf(s.w + bi.w, 0.0f);
    uint2 o;
    o.x = (unsigned)f2bf(s.x) | ((unsigned)f2bf(s.y) << 16);
    o.y = (unsigned)f2bf(s.z) | ((unsigned)f2bf(s.w) << 16);
    *(uint2*)&out_bf[i4] = o;
}

// --- fused: split-K reduce (GEMM2) + bias2 + relu + W3 dot + epilogue
__global__ __launch_bounds__(256)
void rowhead_kernel(const float* __restrict__ Cpart,
                    const float* __restrict__ b2,
                    const float* __restrict__ W3,
                    const float* __restrict__ b3,
                    const float* __restrict__ sel,
                    const float* __restrict__ top_score,
                    const unsigned* __restrict__ valid,
                    const unsigned* __restrict__ keep,
                    float* __restrict__ out) {
    __shared__ float red[4][4];
    int r = blockIdx.x, t = threadIdx.x;
    int wave = t >> 6, lane = t & 63;
    int c = t * 4;
    const int MN = MAXD * HID;
    float4 s = *(const float4*)&Cpart[(long)r * HID + c];
#pragma unroll
    for (int z = 1; z < SPLITK; ++z) {
        float4 p = *(const float4*)&Cpart[(long)z * MN + (long)r * HID + c];
        s.x += p.x; s.y += p.y; s.z += p.z; s.w += p.w;
    }
    float4 bi = *(const float4*)&b2[c];
    float h[4];
    h[0] = fmaxf(s.x + bi.x, 0.0f);
    h[1] = fmaxf(s.y + bi.y, 0.0f);
    h[2] = fmaxf(s.z + bi.z, 0.0f);
    h[3] = fmaxf(s.w + bi.w, 0.0f);
    float a0 = 0.f, a1 = 0.f, a2 = 0.f, a3 = 0.f;
#pragma unroll
    for (int i = 0; i < 4; ++i) {
        float4 w = *(const float4*)&W3[(c + i) * 4];
        a0 += h[i] * w.x; a1 += h[i] * w.y;
        a2 += h[i] * w.z; a3 += h[i] * w.w;
    }
#pragma unroll
    for (int off = 32; off > 0; off >>= 1) {
        a0 += __shfl_down(a0, off);
        a1 += __shfl_down(a1, off);
        a2 += __shfl_down(a2, off);
        a3 += __shfl_down(a3, off);
    }
    if (lane == 0) {
        red[wave][0] = a0; red[wave][1] = a1;
        red[wave][2] = a2; red[wave][3] = a3;
    }
    __syncthreads();
    if (t == 0) {
        float d0 = red[0][0] + red[1][0] + red[2][0] + red[3][0] + b3[0];
        float d1 = red[0][1] + red[1][1] + red[2][1] + red[3][1] + b3[1];
        float d2 = red[0][2] + red[1][2] + red[2][2] + red[3][2] + b3[2];
        float d3 = red[0][3] + red[1][3] + red[2][3] + red[3][3] + b3[3];
        if (keep[r] != 0u) {
            float4 b = ((const float4*)sel)[r];
            float acx = b.x + 0.5f * b.z;
            float acy = b.y + 0.5f * b.w;
            float cx = acx + d0 * b.z;
            float cy = acy + d1 * b.w;
            float nw = b.z * expf(d2);
            float nh = b.w * expf(d3);
            out[r * 5 + 0] = cx - 0.5f * nw;
            out[r * 5 + 1] = cy - 0.5f * nh;
            out[r * 5 + 2] = nw;
            out[r * 5 + 3] = nh;
            out[r * 5 + 4] = (valid[r] != 0u) ? top_score[r] : 0.0f;
        } else {
            out[r * 5 + 0] = 0.0f;
            out[r * 5 + 1] = 0.0f;
            out[r * 5 + 2] = 0.0f;
            out[r * 5 + 3] = 0.0f;
            out[r * 5 + 4] = 0.0f;
        }
    }
}

// ---------------------------------------------------------------- host
extern "C" void kernel_launch(void* const* d_in, const int* in_sizes, int n_in,
                              void* d_out, int out_size, void* d_ws, size_t ws_size,
                              hipStream_t stream) {
    const float* features = (const float*)d_in[0];
    const float* rpn_obj  = (const float*)d_in[1];
    const float* rpn_reg  = (const float*)d_in[2];
    const float* anchors  = (const float*)d_in[3];
    const float* W1 = (const float*)d_in[4];
    const float* b1 = (const float*)d_in[5];
    const float* W2 = (const float*)d_in[6];
    const float* b2 = (const float*)d_in[7];
    const float* W3 = (const float*)d_in[8];
    const float* b3 = (const float*)d_in[9];
    float* out = (float*)d_out;

    char* ws = (char*)d_ws;
    size_t off = 0;
    auto alloc = [&](size_t bytes) {
        char* p = ws + off;
        off += (bytes + 255) & ~(size_t)255;
        return p;
    };
    unsigned* hist      = (unsigned*)alloc(NBUCK * sizeof(unsigned));
    unsigned long long* bins =
        (unsigned long long*)alloc((size_t)NBUCK * BINCAP * 8);
    float*    sel       = (float*)alloc(MAXD * 4 * sizeof(float));
    float*    top_score = (float*)alloc(MAXD * sizeof(float));
    unsigned* valid     = (unsigned*)alloc(MAXD * sizeof(unsigned));
    unsigned* keep      = (unsigned*)alloc(MAXD * sizeof(unsigned));
    unsigned long long* mask = (unsigned long long*)alloc(MAXD * 8 * 8);
    unsigned short* pooled = (unsigned short*)alloc((size_t)MAXD * FIN * 2);
    unsigned short* W1t = (unsigned short*)alloc((size_t)FIN * HID * 2);
    unsigned short* W2t = (unsigned short*)alloc((size_t)HID * HID * 2);
    unsigned short* h1  = (unsigned short*)alloc((size_t)MAXD * HID * 2);
    float*    Cpart     = (float*)alloc((size_t)SPLITK * MAXD * HID * sizeof(float));
    (void)ws_size; (void)in_sizes; (void)n_in; (void)out_size;

    const int TBLOCKS = (FIN / 32) * (HID / 32) + (HID / 32) * (HID / 32);
    hipMemsetAsync(hist, 0, NBUCK * sizeof(unsigned), stream);
    front_kernel<<<256 + TBLOCKS, 256, 0, stream>>>(rpn_obj, hist, bins,
                                                    W1, W1t, W2, W2t);
    tgs_kernel<<<1, 1024, 0, stream>>>(hist, bins, rpn_reg, anchors,
                                       sel, top_score, valid);
    // roialign (4608 blocks) + iou rows (512 blocks), both need only sel
    roialign_iou_kernel<<<MAXD * 9 + MAXD, 256, 0, stream>>>(features, sel,
                                                             pooled, mask);
    const int MN = MAXD * HID;
    // GEMM1 (512 blocks) + 1 tail block running the NMS scan concurrently
    mfma_gemm_kernel<<<GEMM_BLOCKS + 1, 256, 0, stream>>>(
        pooled, W1t, Cpart, FIN, mask, valid, keep);
    reduce_bias_relu_kernel<<<MN / 4 / 256, 256, 0, stream>>>(
        Cpart, b1, h1, MN, HID);
    mfma_gemm_kernel<<<GEMM_BLOCKS, 256, 0, stream>>>(
        h1, W2t, Cpart, HID, nullptr, nullptr, nullptr);
    rowhead_kernel<<<MAXD, 256, 0, stream>>>(Cpart, b2, W3, b3, sel,
                                             top_score, valid, keep, out);
}

// Round 6
// 172.177 us; speedup vs baseline: 1.2590x; 1.0461x over previous
//
#include <hip/hip_runtime.h>
#include <math.h>

#define HFD 128
#define WFD 128
#define DFD 512
#define KA  4
#define NA  (HFD*WFD*KA)      // 65536
#define MAXD 512
#define HID 1024
#define FIN 4608              // 3*3*512
#define NBUCK 1025
#define BINCAP 64
#define TAUF 0.5f
#define NMS_THR 0.3f
#define SPLITK 4
#define GEMM_BLOCKS (16 * 8 * SPLITK)   // N/64 x M/64 x SPLITK = 512
#define TBLOCKS ((FIN / 32) * (HID / 32) + (HID / 32) * (HID / 32))  // 5632

typedef __bf16 bf16x8 __attribute__((ext_vector_type(8)));
typedef float  floatx4 __attribute__((ext_vector_type(4)));

__device__ __forceinline__ unsigned short f2bf(float x) {
    unsigned u = __float_as_uint(x);
    unsigned r = (u + 0x7FFFu + ((u >> 16) & 1u)) >> 16;   // RNE
    return (unsigned short)r;
}

__device__ __forceinline__ unsigned long long rdlane64(unsigned long long v, int b) {
    unsigned lo = (unsigned)__builtin_amdgcn_readlane((int)(unsigned)v, b);
    unsigned hi = (unsigned)__builtin_amdgcn_readlane((int)(unsigned)(v >> 32), b);
    return ((unsigned long long)hi << 32) | lo;
}

// ---- front: score+bucket-bin only (256 blocks) — shortest path to tgs
__global__ __launch_bounds__(256)
void front_kernel(const float* __restrict__ rpn_obj,
                  unsigned* __restrict__ hist,
                  unsigned long long* __restrict__ bins) {
    int n = blockIdx.x * 256 + threadIdx.x;
    float2 o = ((const float2*)rpn_obj)[n];
    float m  = fmaxf(o.x, o.y);
    float e0 = expf(o.x - m), e1 = expf(o.y - m);
    float s  = e1 / (e0 + e1);
    if (s > TAUF) {
        unsigned bits = __float_as_uint(s);
        unsigned bk = (bits - 0x3F000000u) >> 13;     // 0..1024
        unsigned slot = atomicAdd(&hist[bk], 1u);
        if (slot < BINCAP)
            bins[bk * BINCAP + slot] =
                ((unsigned long long)bits << 32) |
                (unsigned long long)(~(unsigned)n);
    }
}

// ---- single block: threshold + gather + register bitonic + decode
// Suffix-sum via shfl wave-scan (4 barriers, was ~22); sort keeps the key
// in a register: j<=32 phases via shfl_xor (no barrier), only j>=64 via
// LDS (10 of 55 phases). Gather count is provably <= 576 -> SN=1024.
__global__ __launch_bounds__(1024)
void tgs_kernel(const unsigned* __restrict__ hist,
                const unsigned long long* __restrict__ bins,
                const float* __restrict__ rpn_reg,
                const float* __restrict__ anchors,
                float* __restrict__ sel,          // 512 x float4
                float* __restrict__ top_score,    // 512
                unsigned* __restrict__ valid_g) { // 512
    __shared__ unsigned long long keys[1024];     // 8 KB
    __shared__ unsigned Hs[NBUCK];                // 4.1 KB
    __shared__ unsigned wsum[16];
    __shared__ unsigned cntS;
    __shared__ unsigned thrS;

    int tid = threadIdx.x;
    int wave = tid >> 6, lane = tid & 63;

    // ---- phase A: load hist, shfl-based suffix-sum, find threshold
    if (tid == 0) cntS = 0u;
    for (int i = tid; i < NBUCK; i += 1024) Hs[i] = hist[i];
    __syncthreads();
    unsigned sfx = Hs[tid + 1];                   // thread t <-> bucket t+1
#pragma unroll
    for (int d = 1; d < 64; d <<= 1) {            // wave suffix scan
        unsigned v = __shfl_down(sfx, d);
        if (lane + d < 64) sfx += v;
    }
    if (lane == 0) wsum[wave] = sfx;
    __syncthreads();
    if (wave == 0) {                              // suffix strictly above wave
        unsigned orig = (lane < 16) ? wsum[lane] : 0u;
        unsigned s = orig;
#pragma unroll
        for (int d = 1; d < 16; d <<= 1) {
            unsigned v = __shfl_down(s, d);
            if (lane + d < 64) s += v;
        }
        if (lane < 16) wsum[lane] = s - orig;
    }
    __syncthreads();
    unsigned above = wsum[wave];
    unsigned Scur = sfx + above;                  // suffix incl bucket tid+1
    unsigned nx = __shfl_down(Scur, 1);
    unsigned Snxt = (lane == 63) ? above : nx;    // Ssc[tid+1] (wave15: 0)
    if (tid == 0 && Scur < MAXD) thrS = 0u;
    if (Scur >= MAXD && Snxt < MAXD) thrS = (unsigned)(tid + 1);
    __syncthreads();
    unsigned thr = thrS;

    // ---- phase B: wave-per-bucket PARALLEL gather (lane i -> slot i)
    for (int b = (int)thr + wave; b < NBUCK; b += 16) {
        unsigned c = Hs[b]; if (c > BINCAP) c = BINCAP;
        unsigned base = 0;
        if (lane == 0 && c > 0) base = atomicAdd(&cntS, c);
        base = __shfl(base, 0);
        if (c > 0 && lane < c && base + lane < 1024)
            keys[base + lane] = bins[(long)b * BINCAP + lane];
    }
    __syncthreads();
    unsigned cnt = cntS; if (cnt > 1024) cnt = 1024;
    if (tid >= (int)cnt) keys[tid] = 0ULL;
    __syncthreads();

    // ---- phase C: bitonic sort descending, key in register
    unsigned long long k64 = keys[tid];
#pragma unroll
    for (int k = 2; k <= 1024; k <<= 1) {
        for (int j = k >> 1; j >= 64; j >>= 1) {  // cross-wave via LDS
            keys[tid] = k64;
            __syncthreads();
            unsigned long long v = keys[tid ^ j];
            bool takemax = (((tid & j) == 0) == ((tid & k) == 0));
            k64 = takemax ? (k64 >= v ? k64 : v) : (k64 <= v ? k64 : v);
            __syncthreads();
        }
        int js = ((k >> 1) < 32) ? (k >> 1) : 32;
        for (int j = js; j >= 1; j >>= 1) {       // intra-wave via shfl_xor
            unsigned lo = __shfl_xor((unsigned)k64, j);
            unsigned hi = __shfl_xor((unsigned)(k64 >> 32), j);
            unsigned long long v = ((unsigned long long)hi << 32) | lo;
            bool takemax = (((tid & j) == 0) == ((tid & k) == 0));
            k64 = takemax ? (k64 >= v ? k64 : v) : (k64 <= v ? k64 : v);
        }
    }

    // ---- phase D: decode top-512 boxes from register (same fp32 formulas)
    if (tid < MAXD) {
        unsigned sbits = (unsigned)(k64 >> 32);
        bool v = (sbits != 0u);
        unsigned idx = v ? (unsigned)(~(unsigned)k64) : 0u;
        int cell = idx >> 2, kk = idx & 3;
        float4 rg = *(const float4*)&rpn_reg[cell * 16 + 4 * kk];
        float4 an = *(const float4*)&anchors[idx * 4];
        float acx = an.x + an.z * 0.5f;
        float acy = an.y + an.w * 0.5f;
        float cx = acx + rg.x * an.z;
        float cy = acy + rg.y * an.w;
        float w  = an.z * expf(rg.z);
        float h  = an.w * expf(rg.w);
        ((float4*)sel)[tid] = make_float4(cx - 0.5f * w, cy - 0.5f * h, w, h);
        top_score[tid] = v ? __uint_as_float(sbits) : 0.0f;
        valid_g[tid]   = v ? 1u : 0u;
    }
}

// ---- ROI align (blocks 0..4607) + IoU rows (4608..5119) + weight
//      transposes (5120..10751). roialign/iou need sel; transposes need
//      only W1/W2 and are consumed one launch later (GEMM1/GEMM2).
__global__ __launch_bounds__(256)
void roialign_iou_kernel(const float* __restrict__ feat,
                         const float* __restrict__ sel,
                         unsigned short* __restrict__ pooled,
                         unsigned long long* __restrict__ mask,
                         const float* __restrict__ W1,
                         unsigned short* __restrict__ W1t,
                         const float* __restrict__ W2,
                         unsigned short* __restrict__ W2t) {
    __shared__ float tile[32][33];
    int blk = blockIdx.x;
    if (blk >= MAXD * 9 + MAXD) {
        // -------- weight transpose tile (fp32 -> bf16, W^T layout)
        int b = blk - (MAXD * 9 + MAXD);
        const float* W; unsigned short* Wt; int K, N;
        if (b < (FIN / 32) * (HID / 32)) { W = W1; Wt = W1t; K = FIN; N = HID; }
        else { b -= (FIN / 32) * (HID / 32); W = W2; Wt = W2t; K = HID; N = HID; }
        int bn = (b & (N / 32 - 1)) * 32;
        int bk = (b / (N / 32)) * 32;
        int tx = threadIdx.x & 31, ty = threadIdx.x >> 5;     // ty 0..7
#pragma unroll
        for (int r = 0; r < 32; r += 8)
            tile[ty + r][tx] = W[(long)(bk + ty + r) * N + bn + tx];
        __syncthreads();
#pragma unroll
        for (int r = 0; r < 32; r += 8)
            Wt[(long)(bn + ty + r) * K + bk + tx] = f2bf(tile[tx][ty + r]);
        return;
    }
    if (blk >= MAXD * 9) {
        // -------- IoU row: thread t covers cols t and t+256
        int i = blk - MAXD * 9;
        int t = threadIdx.x, wv = t >> 6, lane = t & 63;
        float4 bi = ((const float4*)sel)[i];
        float x2i = bi.x + bi.z, y2i = bi.y + bi.w;
        float ai = bi.z * bi.w;
#pragma unroll
        for (int h = 0; h < 2; ++h) {
            int j = h * 256 + wv * 64 + lane;
            float4 bj = ((const float4*)sel)[j];
            float x2j = bj.x + bj.z, y2j = bj.y + bj.w;
            float aj = bj.z * bj.w;
            float ix = fmaxf(0.0f, fminf(x2i, x2j) - fmaxf(bi.x, bj.x));
            float iy = fmaxf(0.0f, fminf(y2i, y2j) - fmaxf(bi.y, bj.y));
            float inter = ix * iy;
            float iou = inter / (ai + aj - inter + 1e-8f);
            unsigned long long bal = __ballot(iou > NMS_THR);
            if (lane == 0) mask[i * 8 + h * 4 + wv] = bal;
        }
        return;
    }
    // -------- ROI align tile (9 blocks per ROI)
    int mrow = blk / 9;
    int tl = blk - mrow * 9;          // (p>>1)*3 + (q>>1)
    int tp = tl / 3, tq = tl - tp * 3;
    int c = threadIdx.x;              // channels c and c+256
    float4 b = ((const float4*)sel)[mrow];
    float vmax0 = -INFINITY, vmax1 = -INFINITY;
#pragma unroll
    for (int dp = 0; dp < 2; ++dp) {
        int p = tp * 2 + dp;
        float fy = (b.y + ((float)p + 0.5f) / 6.0f * b.w) / 16.0f - 0.5f;
        fy = fminf(fmaxf(fy, 0.0f), 127.0f);
        int y0 = (int)floorf(fy);
        int y1 = min(y0 + 1, 127);
        float wy = fy - (float)y0;
#pragma unroll
        for (int dq = 0; dq < 2; ++dq) {
            int q = tq * 2 + dq;
            float fx = (b.x + ((float)q + 0.5f) / 6.0f * b.z) / 16.0f - 0.5f;
            fx = fminf(fmaxf(fx, 0.0f), 127.0f);
            int x0 = (int)floorf(fx);
            int x1 = min(x0 + 1, 127);
            float wx = fx - (float)x0;
            const float* f00 = feat + (y0 * WFD + x0) * DFD;
            const float* f01 = feat + (y0 * WFD + x1) * DFD;
            const float* f10 = feat + (y1 * WFD + x0) * DFD;
            const float* f11 = feat + (y1 * WFD + x1) * DFD;
            float w00 = (1.0f - wy) * (1.0f - wx);
            float w01 = (1.0f - wy) * wx;
            float w10 = wy * (1.0f - wx);
            float w11 = wy * wx;
            float v0 = f00[c] * w00 + f01[c] * w01 + f10[c] * w10 + f11[c] * w11;
            float v1 = f00[c + 256] * w00 + f01[c + 256] * w01 +
                       f10[c + 256] * w10 + f11[c + 256] * w11;
            vmax0 = fmaxf(vmax0, v0);
            vmax1 = fmaxf(vmax1, v1);
        }
    }
    pooled[mrow * FIN + tl * DFD + c] = f2bf(vmax0);
    pooled[mrow * FIN + tl * DFD + c + 256] = f2bf(vmax1);
}

// --------------------------------------- bf16 MFMA GEMM with split-K
// LDK=64 + XOR slot swizzle (slot ^= row&7): staging writes AND fragment
// reads are <=2-way bank conflicts (old LDK=72 writes were 8-way,
// SQ_LDS_BANK_CONFLICT=1.47M in round-4 PMC). One extra tail block runs
// the NMS scalar-closure scan when mask != nullptr.
#define LDK 64
__device__ __forceinline__ int swz(int row, int cs) {
    return row * LDK + (cs ^ ((row & 7) << 3));   // cs in shorts, mult of 8
}
__global__ __launch_bounds__(256)
void mfma_gemm_kernel(const unsigned short* __restrict__ A,
                      const unsigned short* __restrict__ Bt,
                      float* __restrict__ Cpart,
                      int K,
                      const unsigned long long* __restrict__ mask,
                      const unsigned* __restrict__ valid,
                      unsigned* __restrict__ keep) {
    int blk = blockIdx.x;
    if (blk >= GEMM_BLOCKS) {
        // -------- NMS scalar-closure tail (1 wave; per-kept-box chain)
        int lane = threadIdx.x;
        if (lane >= 64) return;
        unsigned long long vb[8];
#pragma unroll
        for (int g = 0; g < 8; ++g)
            vb[g] = __ballot(valid[g * 64 + lane] != 0u);
        unsigned long long cw[8], cwn[8];
#pragma unroll
        for (int g = 0; g < 8; ++g)
            cw[g] = mask[(g * 64 + lane) * 8 + 0];
        unsigned supp8 = 0u;
#pragma unroll
        for (int G = 0; G < 8; ++G) {
            if (G < 7) {
#pragma unroll
                for (int g = 0; g < 8; ++g)
                    cwn[g] = mask[(g * 64 + lane) * 8 + (G + 1)];
            }
            unsigned long long alive =
                vb[G] & ~__ballot((supp8 >> G) & 1u);
            unsigned long long Kw = 0ULL;
            while (alive) {                       // wave-uniform scalar loop
                int b = __builtin_ctzll(alive);
                Kw |= 1ULL << b;
                unsigned long long row = rdlane64(cw[G], b);
                alive &= ~row;
                alive &= ~(1ULL << b);
            }
            keep[G * 64 + lane] = (unsigned)((Kw >> lane) & 1ULL);
#pragma unroll
            for (int g = 0; g < 8; ++g) {
                supp8 |= ((cw[g] & Kw) != 0ULL ? 1u : 0u) << g;
                cw[g] = cwn[g];
            }
        }
        return;
    }

    __shared__ unsigned short As[64 * LDK];       // 8 KB
    __shared__ unsigned short Bs[64 * LDK];       // 8 KB
    int tid = threadIdx.x;
    int wave = tid >> 6, lane = tid & 63;
    int bz = blk >> 7;            // / (16*8)
    int rem = blk & 127;
    int bm = (rem >> 4) * 64, bn = (rem & 15) * 64;
    int KC = K / SPLITK;
    int ks = bz * KC;

    floatx4 acc[4] = {};
    int lr = tid >> 2;            // 0..63  staging row
    int lk = (tid & 3) << 4;      // 0,16,32,48  staging k-offset (shorts)
    int frow = lane & 15, quad = lane >> 4;

    const unsigned short* Ap = A + (long)(bm + lr) * K + lk;
    const unsigned short* Bp = Bt + (long)(bn + lr) * K + lk;
    int ra = wave * 16 + frow;

    for (int k0 = ks; k0 < ks + KC; k0 += 64) {
        uint4 a0 = *(const uint4*)(Ap + k0);
        uint4 a1 = *(const uint4*)(Ap + k0 + 8);
        uint4 b0 = *(const uint4*)(Bp + k0);
        uint4 b1 = *(const uint4*)(Bp + k0 + 8);
        *(uint4*)&As[swz(lr, lk)] = a0;
        *(uint4*)&As[swz(lr, lk + 8)] = a1;
        *(uint4*)&Bs[swz(lr, lk)] = b0;
        *(uint4*)&Bs[swz(lr, lk + 8)] = b1;
        __syncthreads();
        bf16x8 af0 = *(const bf16x8*)&As[swz(ra, quad * 8)];
        bf16x8 af1 = *(const bf16x8*)&As[swz(ra, 32 + quad * 8)];
#pragma unroll
        for (int t = 0; t < 4; ++t) {
            int rb = t * 16 + frow;
            bf16x8 b0v = *(const bf16x8*)&Bs[swz(rb, quad * 8)];
            bf16x8 b1v = *(const bf16x8*)&Bs[swz(rb, 32 + quad * 8)];
            acc[t] = __builtin_amdgcn_mfma_f32_16x16x32_bf16(af0, b0v, acc[t], 0, 0, 0);
            acc[t] = __builtin_amdgcn_mfma_f32_16x16x32_bf16(af1, b1v, acc[t], 0, 0, 0);
        }
        __syncthreads();
    }

    float* Cp = Cpart + (long)bz * MAXD * HID;
#pragma unroll
    for (int t = 0; t < 4; ++t) {
#pragma unroll
        for (int r = 0; r < 4; ++r) {
            int m = bm + wave * 16 + quad * 4 + r;
            int n = bn + t * 16 + frow;
            Cp[(long)m * HID + n] = acc[t][r];
        }
    }
}

// --------------------- split-K reduce + bias + relu -> bf16
__global__ __launch_bounds__(256)
void reduce_bias_relu_kernel(const float* __restrict__ Cpart,
                             const float* __restrict__ bias,
                             unsigned short* __restrict__ out_bf,
                             int MN, int N) {
    int i4 = (blockIdx.x * blockDim.x + threadIdx.x) * 4;
    if (i4 >= MN) return;
    float4 s = *(const float4*)&Cpart[i4];
#pragma unroll
    for (int z = 1; z < SPLITK; ++z) {
        float4 p = *(const float4*)&Cpart[(long)z * MN + i4];
        s.x += p.x; s.y += p.y; s.z += p.z; s.w += p.w;
    }
    int n = i4 & (N - 1);
    float4 bi = *(const float4*)&bias[n];
    s.x = fmaxf(s.x + bi.x, 0.0f);
    s.y = fmaxf(s.y + bi.y, 0.0f);
    s.z = fmaxf(s.z + bi.z, 0.0f);
    s.w = fmaxf(s.w + bi.w, 0.0f);
    uint2 o;
    o.x = (unsigned)f2bf(s.x) | ((unsigned)f2bf(s.y) << 16);
    o.y = (unsigned)f2bf(s.z) | ((unsigned)f2bf(s.w) << 16);
    *(uint2*)&out_bf[i4] = o;
}

// --- fused: split-K reduce (GEMM2) + bias2 + relu + W3 dot + epilogue
__global__ __launch_bounds__(256)
void rowhead_kernel(const float* __restrict__ Cpart,
                    const float* __restrict__ b2,
                    const float* __restrict__ W3,
                    const float* __restrict__ b3,
                    const float* __restrict__ sel,
                    const float* __restrict__ top_score,
                    const unsigned* __restrict__ valid,
                    const unsigned* __restrict__ keep,
                    float* __restrict__ out) {
    __shared__ float red[4][4];
    int r = blockIdx.x, t = threadIdx.x;
    int wave = t >> 6, lane = t & 63;
    int c = t * 4;
    const int MN = MAXD * HID;
    float4 s = *(const float4*)&Cpart[(long)r * HID + c];
#pragma unroll
    for (int z = 1; z < SPLITK; ++z) {
        float4 p = *(const float4*)&Cpart[(long)z * MN + (long)r * HID + c];
        s.x += p.x; s.y += p.y; s.z += p.z; s.w += p.w;
    }
    float4 bi = *(const float4*)&b2[c];
    float h[4];
    h[0] = fmaxf(s.x + bi.x, 0.0f);
    h[1] = fmaxf(s.y + bi.y, 0.0f);
    h[2] = fmaxf(s.z + bi.z, 0.0f);
    h[3] = fmaxf(s.w + bi.w, 0.0f);
    float a0 = 0.f, a1 = 0.f, a2 = 0.f, a3 = 0.f;
#pragma unroll
    for (int i = 0; i < 4; ++i) {
        float4 w = *(const float4*)&W3[(c + i) * 4];
        a0 += h[i] * w.x; a1 += h[i] * w.y;
        a2 += h[i] * w.z; a3 += h[i] * w.w;
    }
#pragma unroll
    for (int off = 32; off > 0; off >>= 1) {
        a0 += __shfl_down(a0, off);
        a1 += __shfl_down(a1, off);
        a2 += __shfl_down(a2, off);
        a3 += __shfl_down(a3, off);
    }
    if (lane == 0) {
        red[wave][0] = a0; red[wave][1] = a1;
        red[wave][2] = a2; red[wave][3] = a3;
    }
    __syncthreads();
    if (t == 0) {
        float d0 = red[0][0] + red[1][0] + red[2][0] + red[3][0] + b3[0];
        float d1 = red[0][1] + red[1][1] + red[2][1] + red[3][1] + b3[1];
        float d2 = red[0][2] + red[1][2] + red[2][2] + red[3][2] + b3[2];
        float d3 = red[0][3] + red[1][3] + red[2][3] + red[3][3] + b3[3];
        if (keep[r] != 0u) {
            float4 b = ((const float4*)sel)[r];
            float acx = b.x + 0.5f * b.z;
            float acy = b.y + 0.5f * b.w;
            float cx = acx + d0 * b.z;
            float cy = acy + d1 * b.w;
            float nw = b.z * expf(d2);
            float nh = b.w * expf(d3);
            out[r * 5 + 0] = cx - 0.5f * nw;
            out[r * 5 + 1] = cy - 0.5f * nh;
            out[r * 5 + 2] = nw;
            out[r * 5 + 3] = nh;
            out[r * 5 + 4] = (valid[r] != 0u) ? top_score[r] : 0.0f;
        } else {
            out[r * 5 + 0] = 0.0f;
            out[r * 5 + 1] = 0.0f;
            out[r * 5 + 2] = 0.0f;
            out[r * 5 + 3] = 0.0f;
            out[r * 5 + 4] = 0.0f;
        }
    }
}

// ---------------------------------------------------------------- host
extern "C" void kernel_launch(void* const* d_in, const int* in_sizes, int n_in,
                              void* d_out, int out_size, void* d_ws, size_t ws_size,
                              hipStream_t stream) {
    const float* features = (const float*)d_in[0];
    const float* rpn_obj  = (const float*)d_in[1];
    const float* rpn_reg  = (const float*)d_in[2];
    const float* anchors  = (const float*)d_in[3];
    const float* W1 = (const float*)d_in[4];
    const float* b1 = (const float*)d_in[5];
    const float* W2 = (const float*)d_in[6];
    const float* b2 = (const float*)d_in[7];
    const float* W3 = (const float*)d_in[8];
    const float* b3 = (const float*)d_in[9];
    float* out = (float*)d_out;

    char* ws = (char*)d_ws;
    size_t off = 0;
    auto alloc = [&](size_t bytes) {
        char* p = ws + off;
        off += (bytes + 255) & ~(size_t)255;
        return p;
    };
    unsigned* hist      = (unsigned*)alloc(NBUCK * sizeof(unsigned));
    unsigned long long* bins =
        (unsigned long long*)alloc((size_t)NBUCK * BINCAP * 8);
    float*    sel       = (float*)alloc(MAXD * 4 * sizeof(float));
    float*    top_score = (float*)alloc(MAXD * sizeof(float));
    unsigned* valid     = (unsigned*)alloc(MAXD * sizeof(unsigned));
    unsigned* keep      = (unsigned*)alloc(MAXD * sizeof(unsigned));
    unsigned long long* mask = (unsigned long long*)alloc(MAXD * 8 * 8);
    unsigned short* pooled = (unsigned short*)alloc((size_t)MAXD * FIN * 2);
    unsigned short* W1t = (unsigned short*)alloc((size_t)FIN * HID * 2);
    unsigned short* W2t = (unsigned short*)alloc((size_t)HID * HID * 2);
    unsigned short* h1  = (unsigned short*)alloc((size_t)MAXD * HID * 2);
    float*    Cpart     = (float*)alloc((size_t)SPLITK * MAXD * HID * sizeof(float));
    (void)ws_size; (void)in_sizes; (void)n_in; (void)out_size;

    hipMemsetAsync(hist, 0, NBUCK * sizeof(unsigned), stream);
    front_kernel<<<256, 256, 0, stream>>>(rpn_obj, hist, bins);
    tgs_kernel<<<1, 1024, 0, stream>>>(hist, bins, rpn_reg, anchors,
                                       sel, top_score, valid);
    // roialign (4608) + iou (512) + weight transposes (5632)
    roialign_iou_kernel<<<MAXD * 9 + MAXD + TBLOCKS, 256, 0, stream>>>(
        features, sel, pooled, mask, W1, W1t, W2, W2t);
    const int MN = MAXD * HID;
    // GEMM1 (512 blocks) + 1 tail block running the NMS scan concurrently
    mfma_gemm_kernel<<<GEMM_BLOCKS + 1, 256, 0, stream>>>(
        pooled, W1t, Cpart, FIN, mask, valid, keep);
    reduce_bias_relu_kernel<<<MN / 4 / 256, 256, 0, stream>>>(
        Cpart, b1, h1, MN, HID);
    mfma_gemm_kernel<<<GEMM_BLOCKS, 256, 0, stream>>>(
        h1, W2t, Cpart, HID, nullptr, nullptr, nullptr);
    rowhead_kernel<<<MAXD, 256, 0, stream>>>(Cpart, b2, W3, b3, sel,
                                             top_score, valid, keep, out);
}